// Round 13
// baseline (135.898 us; speedup 1.0000x reference)
//
#include <hip/hip_runtime.h>
#include <hip/hip_bf16.h>
#include <math.h>
#include <limits.h>

// Problem constants (fixed by setup_inputs)
#define BS 2
#define NW 5
#define NS 5
#define NQ 5
#define FDIM 64
#define FH 21
#define FW 21
#define NPOS (FH*FW)            // 441
#define NIMG (BS*NW*(NS+NQ))    // 100
#define NQIMG 50
#define IMG_ELEMS (FDIM*NPOS)   // 28224
#define NY (NS*NPOS)            // 2205
#define QROWS 448               // 441 padded to 28*16
#define SROWS 2208              // 138 tiles of 16 rows; rows 2205..2207 zeroed
#define NSLICE 6                // y split: 138 = 6 * 23
#define NT_S 23                 // y-tiles per slice (23 KB LDS)
#define NBLK 250
#define NBLK_SIM (NBLK*NSLICE)  // 1500
#define TILE_B 1024             // 16 rows x 64 B (i8) per tile

typedef __attribute__((ext_vector_type(4))) int int4v;

static __device__ __forceinline__ unsigned short f2bf(float x) {
    union { float f; unsigned u; } v; v.f = x;
    unsigned r = v.u + 0x7fffu + ((v.u >> 16) & 1u);
    return (unsigned short)(r >> 16);
}

static __device__ __forceinline__ float bf2f(unsigned short u) {
    union { unsigned u; float f; } v; v.u = ((unsigned)u) << 16;
    return v.f;
}

static __device__ __forceinline__ void gload_lds16(const void* g, void* l) {
    __builtin_amdgcn_global_load_lds((const __attribute__((address_space(1))) void*)g,
                                     (__attribute__((address_space(3))) void*)l, 16, 0, 0);
}

static __device__ __forceinline__ int med3i(int a, int b, int c) {
    int r;
    asm("v_med3_i32 %0, %1, %2, %3" : "=v"(r) : "v"(a), "v"(b), "v"(c));
    return r;
}

// rule-17 keep-alive: keeps all 4 elements live without cost
#define KEEP4(p) asm volatile("" :: "v"((p)[0]), "v"((p)[1]), "v"((p)[2]), "v"((p)[3]))

// Insert d into sorted int top-3 (a0>=a1>=a2): max + 2x med3 (3 VALU ops, depth 1)
#define T3I(d, a0, a1, a2) do { \
    int _n0 = ((d) > (a0)) ? (d) : (a0); \
    int _n1 = med3i((d), (a0), (a1)); \
    int _n2 = med3i((d), (a1), (a2)); \
    (a0) = _n0; (a1) = _n1; (a2) = _n2; } while (0)

#define T3I4(p, i) do { \
    T3I((p)[0], t0[i], t1[i], t2[i]); \
    T3I((p)[1], t0[i], t1[i], t2[i]); \
    T3I((p)[2], t0[i], t1[i], t2[i]); \
    T3I((p)[3], t0[i], t1[i], t2[i]); } while (0)

// float top-3 insert for the merge kernel
#define T3F(d, a0, a1, a2) do { \
    float _n0 = fmaxf((d), (a0)); \
    float _n1 = __builtin_amdgcn_fmed3f((d), (a0), (a1)); \
    float _n2 = __builtin_amdgcn_fmed3f((d), (a1), (a2)); \
    (a0) = _n0; (a1) = _n1; (a2) = _n2; } while (0)

// Kernel A: L2-normalize per (img,pos), quantize to i8 (scale 127, RNE).
__global__ __launch_bounds__(256) void dn4_normalize(const float* __restrict__ fm,
                                                     const int* __restrict__ elabel,
                                                     char* __restrict__ Qn,
                                                     char* __restrict__ Sn,
                                                     float* __restrict__ out) {
    int gid = blockIdx.x * blockDim.x + threadIdx.x;
    if (gid < 50) {   // label pass-through: out[250+gid]
        int bb = gid / 25, rem = gid % 25, wq = rem / 5, qi = rem % 5;
        out[250 + gid] = (float)elabel[(bb * NW + wq) * (NS + NQ) + NS + qi];
    }
    if (gid < 120) {  // zero S pad rows 2205..2207: 10 mats x 3 rows x 4 int4
        int mat = gid / 12, rr = (gid % 12) >> 2, k = gid & 3;
        int4v zv = {0, 0, 0, 0};
        *(int4v*)(Sn + (size_t)mat * (SROWS * FDIM) + (size_t)(NY + rr) * FDIM + k * 16) = zv;
    }
    if (gid >= NIMG * NPOS) return;
    int img = gid / NPOS;
    int pos = gid - img * NPOS;
    const float* src = fm + (size_t)img * IMG_ELEMS + pos;
    float v[FDIM];
    float ss = 0.f;
#pragma unroll
    for (int c = 0; c < FDIM; ++c) {
        float x = src[(size_t)c * NPOS];
        v[c] = x;
        ss += x * x;
    }
    float rn = 127.0f / (sqrtf(ss) + 1e-12f);
    int w[16];
#pragma unroll
    for (int k = 0; k < 16; ++k) {
        int q0 = __float2int_rn(v[4 * k]     * rn);
        int q1 = __float2int_rn(v[4 * k + 1] * rn);
        int q2 = __float2int_rn(v[4 * k + 2] * rn);
        int q3 = __float2int_rn(v[4 * k + 3] * rn);
        w[k] = (q0 & 0xff) | ((q1 & 0xff) << 8) | ((q2 & 0xff) << 16) | (q3 << 24);
    }
    char* dst;
    int i10 = img % 10;
    if (i10 < NS) {
        int bw = img / 10;
        dst = Sn + (size_t)bw * (SROWS * FDIM) + (size_t)(i10 * NPOS + pos) * FDIM;
    } else {
        int qidx = (img / 10) * NQ + (i10 - NS);
        dst = Qn + (size_t)qidx * (QROWS * FDIM) + (size_t)pos * FDIM;
    }
#pragma unroll
    for (int k = 0; k < 4; ++k) {
        int4v t = {w[4 * k], w[4 * k + 1], w[4 * k + 2], w[4 * k + 3]};
        *(int4v*)(dst + 16 * k) = t;
    }
}

// Kernel B (ABLATION TEMPLATE): r11 geometry — 1500 blocks=(bid,slice), 448 thr
// = 7 waves (wave=xg, 4 x-tiles each), 23-tile LDS slice, swizzle, i8 MFMA.
//   V=0: full r11 inner loop (2-deep stagger)            -> real gtop3
//   V=1: MFMA+LDS only (T3I removed, results kept alive) -> scratch
//   V=2: VALU+LDS only (T3I on raw LDS data, no MFMA)    -> scratch
//   V=3: LDS+loop skeleton only                          -> scratch
//   V=4: full math, 4-deep MFMA issue-ahead              -> scratch
template<int V>
__global__ __launch_bounds__(448, 4) void dn4_sim(const char* __restrict__ Qn,
                                                  const char* __restrict__ Sn,
                                                  unsigned short* __restrict__ gtop3) {
    __shared__ __align__(16) char stile[NT_S][TILE_B];   // 23,552 B

    // m204 bijective chunked XCD swizzle over 1500 units (1500 = 8*187+4)
    int orig = blockIdx.x;
    int xcd = orig & 7, idx = orig >> 3;
    int unit = (xcd < 4 ? xcd * 188 : 4 * 188 + (xcd - 4) * 187) + idx;
    int bid = unit / NSLICE, ys = unit % NSLICE;

    int w = bid % NW;
    int q = (bid / NW) % (NW * NQ);
    int b = bid / (NW * NW * NQ);
    int wq = q / NQ, qi = q % NQ;
    int qidx = (b * NW + wq) * NQ + qi;

    const char* qbase = Qn + (size_t)qidx * (QROWS * FDIM);
    const char* sbase = Sn + (size_t)(b * NW + w) * (SROWS * FDIM);

    int t = threadIdx.x;
    int lane = t & 63, xg = t >> 6;
    int lo16 = lane & 15, hi4 = lane >> 4;

    // Stage source pre-swizzle: LDS linear [row][c] gets global [row][c ^ ((row>>1)&3)]
    int stg0 = ((lane >> 2) * FDIM) + ((((lane & 3) ^ ((lane >> 3) & 3)) << 4));
    int tbase = ys * NT_S;

    for (int i = xg; i < NT_S; i += 7)
        gload_lds16(sbase + (size_t)(tbase + i) * TILE_B + stg0, &stile[i][0]);

    // B fragments (Q): col = lo16 -> x = xt*16+lo16, k = hi4*16 .. +16
    int4v bq[4];
#pragma unroll
    for (int i = 0; i < 4; ++i) {
        int xt = xg * 4 + i;
        bq[i] = *(const int4v*)(qbase + (size_t)(xt * 16 + lo16) * FDIM + hi4 * 16);
    }

    asm volatile("s_waitcnt vmcnt(0)" ::: "memory");
    __syncthreads();   // the ONLY barrier

    if constexpr (V == 2 || V == 3) {   // keep bq loads alive when MFMA absent
        KEEP4(bq[0]); KEEP4(bq[1]); KEEP4(bq[2]); KEEP4(bq[3]);
    }

    int t0[4], t1[4], t2[4];
#pragma unroll
    for (int i = 0; i < 4; ++i) { t0[i] = INT_MIN; t1[i] = INT_MIN; t2[i] = INT_MIN; }

    int4v zc = {0, 0, 0, 0};

    // Swizzled read: row lo16, want col hi4 -> read hi4 ^ ((lo16>>1)&3)
    int rd = lo16 * FDIM + ((hi4 ^ ((lo16 >> 1) & 3)) << 4);

    int4v ca = *(const int4v*)(&stile[0][0] + rd);
    for (int tt = 0; tt < NT_S; ++tt) {
        int4v na = ca;
        if (tt + 1 < NT_S) na = *(const int4v*)(&stile[tt + 1][0] + rd);

        if constexpr (V == 3) {            // LDS + loop skeleton only
            KEEP4(ca);
        } else if constexpr (V == 1) {     // MFMA + LDS only
            int4v pA = __builtin_amdgcn_mfma_i32_16x16x64_i8(ca, bq[0], zc, 0, 0, 0);
            int4v pB = __builtin_amdgcn_mfma_i32_16x16x64_i8(ca, bq[1], zc, 0, 0, 0);
            int4v pC = __builtin_amdgcn_mfma_i32_16x16x64_i8(ca, bq[2], zc, 0, 0, 0);
            int4v pD = __builtin_amdgcn_mfma_i32_16x16x64_i8(ca, bq[3], zc, 0, 0, 0);
            KEEP4(pA); KEEP4(pB); KEEP4(pC); KEEP4(pD);
        } else if constexpr (V == 2) {     // VALU + LDS only (same T3I count as V0)
            T3I4(ca, 0);
            T3I4(ca, 1);
            T3I4(ca, 2);
            T3I4(ca, 3);
        } else if constexpr (V == 4) {     // full math, 4-deep MFMA issue-ahead
            int4v pA = __builtin_amdgcn_mfma_i32_16x16x64_i8(ca, bq[0], zc, 0, 0, 0);
            int4v pB = __builtin_amdgcn_mfma_i32_16x16x64_i8(ca, bq[1], zc, 0, 0, 0);
            int4v pC = __builtin_amdgcn_mfma_i32_16x16x64_i8(ca, bq[2], zc, 0, 0, 0);
            int4v pD = __builtin_amdgcn_mfma_i32_16x16x64_i8(ca, bq[3], zc, 0, 0, 0);
            T3I4(pA, 0);
            T3I4(pB, 1);
            T3I4(pC, 2);
            T3I4(pD, 3);
        } else {                           // V0: r11 2-deep stagger (reference)
            int4v pA = __builtin_amdgcn_mfma_i32_16x16x64_i8(ca, bq[0], zc, 0, 0, 0);
            int4v pB = __builtin_amdgcn_mfma_i32_16x16x64_i8(ca, bq[1], zc, 0, 0, 0);
            T3I4(pA, 0);
            int4v pC = __builtin_amdgcn_mfma_i32_16x16x64_i8(ca, bq[2], zc, 0, 0, 0);
            T3I4(pB, 1);
            int4v pD = __builtin_amdgcn_mfma_i32_16x16x64_i8(ca, bq[3], zc, 0, 0, 0);
            T3I4(pC, 2);
            T3I4(pD, 3);
        }
        ca = na;
    }

    // Merge top-3 across the 4 y-quarter lane-groups (hi4), scale, write bf16
    const float INV = 1.0f / 16129.0f;   // 1/127^2
#pragma unroll
    for (int i = 0; i < 4; ++i) {
        int a0 = t0[i], a1 = t1[i], a2 = t2[i];
#pragma unroll
        for (int mk = 16; mk <= 32; mk <<= 1) {
            int c0 = __shfl_xor(a0, mk, 64);
            int c1 = __shfl_xor(a1, mk, 64);
            int c2 = __shfl_xor(a2, mk, 64);
            T3I(c0, a0, a1, a2);
            T3I(c1, a0, a1, a2);
            T3I(c2, a0, a1, a2);
        }
        if (hi4 == 0) {
            int x = (xg * 4 + i) * 16 + lo16;
            unsigned short* dst = gtop3 + ((size_t)(bid * QROWS + x) * NSLICE + ys) * 3;
            dst[0] = f2bf((float)a0 * INV);
            dst[1] = f2bf((float)a1 * INV);
            dst[2] = f2bf((float)a2 * INV);
        }
    }
}

// Kernel C: merge the 6 y-slices per (bid,x), sum top-3, block-reduce -> out[bid]
__global__ __launch_bounds__(448) void dn4_merge(const unsigned short* __restrict__ gtop3,
                                                 float* __restrict__ out) {
    __shared__ float red[7];
    int bid = blockIdx.x;
    int t = threadIdx.x, lane = t & 63, wv = t >> 6;
    // 18 bf16 per (bid,x) = 9 dwords (36 B stride, 4B aligned)
    const unsigned* p = (const unsigned*)(gtop3 + (size_t)(bid * QROWS + t) * (NSLICE * 3));
    float v[18];
#pragma unroll
    for (int j = 0; j < 9; ++j) {
        unsigned u = p[j];
        v[2 * j]     = bf2f((unsigned short)(u & 0xffffu));
        v[2 * j + 1] = bf2f((unsigned short)(u >> 16));
    }
    float a0 = v[0], a1 = v[1], a2 = v[2];
#pragma unroll
    for (int j = 3; j < 18; ++j) T3F(v[j], a0, a1, a2);
    float s = (t < NPOS) ? (a0 + a1 + a2) : 0.f;
#pragma unroll
    for (int off = 32; off >= 1; off >>= 1) s += __shfl_xor(s, off, 64);
    if (lane == 0) red[wv] = s;
    __syncthreads();
    if (t == 0) {
        float tot = 0.f;
#pragma unroll
        for (int i = 0; i < 7; ++i) tot += red[i];
        out[bid] = tot;
    }
}

extern "C" void kernel_launch(void* const* d_in, const int* in_sizes, int n_in,
                              void* d_out, int out_size, void* d_ws, size_t ws_size,
                              hipStream_t stream) {
    const float* fm     = (const float*)d_in[0];
    const int*   elabel = (const int*)d_in[1];
    float* out = (float*)d_out;

    char* Qn = (char*)d_ws;                                   // 50*448*64 i8   = 1.43 MB
    char* Sn = Qn + (size_t)NQIMG * QROWS * FDIM;             // 10*2208*64 i8  = 1.41 MB
    unsigned short* gtop3  = (unsigned short*)(Sn + (size_t)10 * SROWS * FDIM);  // 4.03 MB (real)
    unsigned short* gtop3b = gtop3 + (size_t)NBLK * QROWS * NSLICE * 3;          // 4.03 MB (scratch)

    int nthreads = NIMG * NPOS;
    dn4_normalize<<<(nthreads + 255) / 256, 256, 0, stream>>>(fm, elabel, Qn, Sn, out);
    dn4_sim<0><<<NBLK_SIM, 448, 0, stream>>>(Qn, Sn, gtop3);    // real
    dn4_sim<1><<<NBLK_SIM, 448, 0, stream>>>(Qn, Sn, gtop3b);   // MFMA-only
    dn4_sim<2><<<NBLK_SIM, 448, 0, stream>>>(Qn, Sn, gtop3b);   // VALU-only
    dn4_sim<3><<<NBLK_SIM, 448, 0, stream>>>(Qn, Sn, gtop3b);   // LDS-only
    dn4_sim<4><<<NBLK_SIM, 448, 0, stream>>>(Qn, Sn, gtop3b);   // 4-deep pipe
    dn4_merge<<<NBLK, 448, 0, stream>>>(gtop3, out);
}

// Round 15
// 118.528 us; speedup vs baseline: 1.1465x; 1.1465x over previous
//
#include <hip/hip_runtime.h>
#include <hip/hip_bf16.h>
#include <math.h>
#include <limits.h>

// Problem constants (fixed by setup_inputs)
#define BS 2
#define NW 5
#define NS 5
#define NQ 5
#define FDIM 64
#define FH 21
#define FW 21
#define NPOS (FH*FW)            // 441
#define NIMG (BS*NW*(NS+NQ))    // 100
#define NQIMG 50
#define IMG_ELEMS (FDIM*NPOS)   // 28224
#define NY (NS*NPOS)            // 2205
#define QROWS 448               // 441 padded to 28*16
#define SROWS 2208              // 138 tiles of 16 rows; rows 2205..2207 zeroed
#define NSLICE 6                // y split: 138 = 6 * 23
#define NT_S 23                 // y-tiles per slice
#define NBLK 250
#define NBLK_SIM (NBLK*NSLICE)  // 1500
#define TILE_B 1024             // 16 rows x 64 B (i8) per tile

typedef __attribute__((ext_vector_type(4))) int int4v;

static __device__ __forceinline__ unsigned short f2bf(float x) {
    union { float f; unsigned u; } v; v.f = x;
    unsigned r = v.u + 0x7fffu + ((v.u >> 16) & 1u);
    return (unsigned short)(r >> 16);
}

static __device__ __forceinline__ float bf2f(unsigned short u) {
    union { unsigned u; float f; } v; v.u = ((unsigned)u) << 16;
    return v.f;
}

static __device__ __forceinline__ void gload_lds16(const void* g, void* l) {
    __builtin_amdgcn_global_load_lds((const __attribute__((address_space(1))) void*)g,
                                     (__attribute__((address_space(3))) void*)l, 16, 0, 0);
}

static __device__ __forceinline__ int med3i(int a, int b, int c) {
    int r;
    asm("v_med3_i32 %0, %1, %2, %3" : "=v"(r) : "v"(a), "v"(b), "v"(c));
    return r;
}

static __device__ __forceinline__ int maxi(int a, int b) {   // forced v_max_i32
    int r;
    asm("v_max_i32 %0, %1, %2" : "=v"(r) : "v"(a), "v"(b));
    return r;
}

// r11-proven top-3 insert (ternary max; 3-4 VALU ops)
#define T3R(d, a0, a1, a2) do { \
    int _n0 = ((d) > (a0)) ? (d) : (a0); \
    int _n1 = med3i((d), (a0), (a1)); \
    int _n2 = med3i((d), (a1), (a2)); \
    (a0) = _n0; (a1) = _n1; (a2) = _n2; } while (0)

// asm-max top-3 insert (certain 3 VALU ops) — diagnostic variant only
#define T3V(d, a0, a1, a2) do { \
    int _n0 = maxi((d), (a0)); \
    int _n1 = med3i((d), (a0), (a1)); \
    int _n2 = med3i((d), (a1), (a2)); \
    (a0) = _n0; (a1) = _n1; (a2) = _n2; } while (0)

#define T3R4(p, s0, s1, s2, i) do { \
    T3R((p)[0], s0[i], s1[i], s2[i]); \
    T3R((p)[1], s0[i], s1[i], s2[i]); \
    T3R((p)[2], s0[i], s1[i], s2[i]); \
    T3R((p)[3], s0[i], s1[i], s2[i]); } while (0)

#define T3V4(p, s0, s1, s2, i) do { \
    T3V((p)[0], s0[i], s1[i], s2[i]); \
    T3V((p)[1], s0[i], s1[i], s2[i]); \
    T3V((p)[2], s0[i], s1[i], s2[i]); \
    T3V((p)[3], s0[i], s1[i], s2[i]); } while (0)

// float top-3 insert for the merge kernel
#define T3F(d, a0, a1, a2) do { \
    float _n0 = fmaxf((d), (a0)); \
    float _n1 = __builtin_amdgcn_fmed3f((d), (a0), (a1)); \
    float _n2 = __builtin_amdgcn_fmed3f((d), (a1), (a2)); \
    (a0) = _n0; (a1) = _n1; (a2) = _n2; } while (0)

// Shared prologue for all sim kernels (swizzle, staging, bq load)
#define SIM_PROLOGUE \
    int orig = blockIdx.x; \
    int xcd = orig & 7, idx = orig >> 3; \
    int unit = (xcd < 4 ? xcd * 188 : 4 * 188 + (xcd - 4) * 187) + idx; \
    int bid = unit / NSLICE, ys = unit % NSLICE; \
    int w = bid % NW; \
    int q = (bid / NW) % (NW * NQ); \
    int b = bid / (NW * NW * NQ); \
    int wq = q / NQ, qi = q % NQ; \
    int qidx = (b * NW + wq) * NQ + qi; \
    const char* qbase = Qn + (size_t)qidx * (QROWS * FDIM); \
    const char* sbase = Sn + (size_t)(b * NW + w) * (SROWS * FDIM); \
    int t = threadIdx.x; \
    int lane = t & 63, xg = t >> 6; \
    int lo16 = lane & 15, hi4 = lane >> 4; \
    int stg0 = ((lane >> 2) * FDIM) + ((((lane & 3) ^ ((lane >> 3) & 3)) << 4)); \
    int tbase = ys * NT_S; \
    for (int i = xg; i < NT_S; i += 7) \
        gload_lds16(sbase + (size_t)(tbase + i) * TILE_B + stg0, &stile[i][0]); \
    int4v bq[4]; \
    _Pragma("unroll") \
    for (int i = 0; i < 4; ++i) { \
        int xt = xg * 4 + i; \
        bq[i] = *(const int4v*)(qbase + (size_t)(xt * 16 + lo16) * FDIM + hi4 * 16); \
    } \
    asm volatile("s_waitcnt vmcnt(0)" ::: "memory"); \
    __syncthreads(); \
    int4v zc = {0, 0, 0, 0}; \
    int rd = lo16 * FDIM + ((hi4 ^ ((lo16 >> 1) & 3)) << 4);

// Kernel A: L2-normalize per (img,pos), quantize to i8 (scale 127, RNE).
__global__ __launch_bounds__(256) void dn4_normalize(const float* __restrict__ fm,
                                                     const int* __restrict__ elabel,
                                                     char* __restrict__ Qn,
                                                     char* __restrict__ Sn,
                                                     float* __restrict__ out) {
    int gid = blockIdx.x * blockDim.x + threadIdx.x;
    if (gid < 50) {   // label pass-through: out[250+gid]
        int bb = gid / 25, rem = gid % 25, wq = rem / 5, qi = rem % 5;
        out[250 + gid] = (float)elabel[(bb * NW + wq) * (NS + NQ) + NS + qi];
    }
    if (gid < 120) {  // zero S pad rows 2205..2207: 10 mats x 3 rows x 4 int4
        int mat = gid / 12, rr = (gid % 12) >> 2, k = gid & 3;
        int4v zv = {0, 0, 0, 0};
        *(int4v*)(Sn + (size_t)mat * (SROWS * FDIM) + (size_t)(NY + rr) * FDIM + k * 16) = zv;
    }
    if (gid >= NIMG * NPOS) return;
    int img = gid / NPOS;
    int pos = gid - img * NPOS;
    const float* src = fm + (size_t)img * IMG_ELEMS + pos;
    float v[FDIM];
    float ss = 0.f;
#pragma unroll
    for (int c = 0; c < FDIM; ++c) {
        float x = src[(size_t)c * NPOS];
        v[c] = x;
        ss += x * x;
    }
    float rn = 127.0f / (sqrtf(ss) + 1e-12f);
    int w[16];
#pragma unroll
    for (int k = 0; k < 16; ++k) {
        int q0 = __float2int_rn(v[4 * k]     * rn);
        int q1 = __float2int_rn(v[4 * k + 1] * rn);
        int q2 = __float2int_rn(v[4 * k + 2] * rn);
        int q3 = __float2int_rn(v[4 * k + 3] * rn);
        w[k] = (q0 & 0xff) | ((q1 & 0xff) << 8) | ((q2 & 0xff) << 16) | (q3 << 24);
    }
    char* dst;
    int i10 = img % 10;
    if (i10 < NS) {
        int bw = img / 10;
        dst = Sn + (size_t)bw * (SROWS * FDIM) + (size_t)(i10 * NPOS + pos) * FDIM;
    } else {
        int qidx = (img / 10) * NQ + (i10 - NS);
        dst = Qn + (size_t)qidx * (QROWS * FDIM) + (size_t)pos * FDIM;
    }
#pragma unroll
    for (int k = 0; k < 4; ++k) {
        int4v t = {w[4 * k], w[4 * k + 1], w[4 * k + 2], w[4 * k + 3]};
        *(int4v*)(dst + 16 * k) = t;
    }
}

// Kernel B (REAL, r11-exact): 2-deep stagger, ternary max. Validated twice.
__global__ __launch_bounds__(448, 4) void dn4_sim_mfma(const char* __restrict__ Qn,
                                                       const char* __restrict__ Sn,
                                                       unsigned short* __restrict__ gtop3) {
    __shared__ __align__(16) char stile[NT_S][TILE_B];
    SIM_PROLOGUE
    int t0[4], t1[4], t2[4];
#pragma unroll
    for (int i = 0; i < 4; ++i) { t0[i] = INT_MIN; t1[i] = INT_MIN; t2[i] = INT_MIN; }

    int4v ca = *(const int4v*)(&stile[0][0] + rd);
    for (int tt = 0; tt < NT_S; ++tt) {
        int4v na = ca;
        if (tt + 1 < NT_S) na = *(const int4v*)(&stile[tt + 1][0] + rd);
        int4v pA = __builtin_amdgcn_mfma_i32_16x16x64_i8(ca, bq[0], zc, 0, 0, 0);
        int4v pB = __builtin_amdgcn_mfma_i32_16x16x64_i8(ca, bq[1], zc, 0, 0, 0);
        T3R4(pA, t0, t1, t2, 0);
        int4v pC = __builtin_amdgcn_mfma_i32_16x16x64_i8(ca, bq[2], zc, 0, 0, 0);
        T3R4(pB, t0, t1, t2, 1);
        int4v pD = __builtin_amdgcn_mfma_i32_16x16x64_i8(ca, bq[3], zc, 0, 0, 0);
        T3R4(pC, t0, t1, t2, 2);
        T3R4(pD, t0, t1, t2, 3);
        ca = na;
    }

    const float INV = 1.0f / 16129.0f;
#pragma unroll
    for (int i = 0; i < 4; ++i) {
        int a0 = t0[i], a1 = t1[i], a2 = t2[i];
#pragma unroll
        for (int mk = 16; mk <= 32; mk <<= 1) {
            int c0 = __shfl_xor(a0, mk, 64);
            int c1 = __shfl_xor(a1, mk, 64);
            int c2 = __shfl_xor(a2, mk, 64);
            T3R(c0, a0, a1, a2);
            T3R(c1, a0, a1, a2);
            T3R(c2, a0, a1, a2);
        }
        if (hi4 == 0) {
            int x = (xg * 4 + i) * 16 + lo16;
            unsigned short* dst = gtop3 + ((size_t)(bid * QROWS + x) * NSLICE + ys) * 3;
            dst[0] = f2bf((float)a0 * INV);
            dst[1] = f2bf((float)a1 * INV);
            dst[2] = f2bf((float)a2 * INV);
        }
    }
}

// DIAGNOSTIC 1: dual-bank pair interleave, ternary max, no garbage-slot read.
// Writes scratch — timing is the payload, values need not validate.
__global__ __launch_bounds__(448, 4) void dn4_pipe(const char* __restrict__ Qn,
                                                   const char* __restrict__ Sn,
                                                   unsigned short* __restrict__ gtop3) {
    __shared__ __align__(16) char stile[NT_S][TILE_B];
    SIM_PROLOGUE
    int tA0[4], tA1[4], tA2[4], tB0[4], tB1[4], tB2[4];
#pragma unroll
    for (int i = 0; i < 4; ++i) {
        tA0[i] = INT_MIN; tA1[i] = INT_MIN; tA2[i] = INT_MIN;
        tB0[i] = INT_MIN; tB1[i] = INT_MIN; tB2[i] = INT_MIN;
    }

#define PROCPAIR(cA, cB) do { \
        int4v pA0 = __builtin_amdgcn_mfma_i32_16x16x64_i8((cA), bq[0], zc, 0, 0, 0); \
        int4v pB0 = __builtin_amdgcn_mfma_i32_16x16x64_i8((cB), bq[0], zc, 0, 0, 0); \
        int4v pA1 = __builtin_amdgcn_mfma_i32_16x16x64_i8((cA), bq[1], zc, 0, 0, 0); \
        int4v pB1 = __builtin_amdgcn_mfma_i32_16x16x64_i8((cB), bq[1], zc, 0, 0, 0); \
        T3R4(pA0, tA0, tA1, tA2, 0); \
        int4v pA2 = __builtin_amdgcn_mfma_i32_16x16x64_i8((cA), bq[2], zc, 0, 0, 0); \
        T3R4(pB0, tB0, tB1, tB2, 0); \
        int4v pB2 = __builtin_amdgcn_mfma_i32_16x16x64_i8((cB), bq[2], zc, 0, 0, 0); \
        T3R4(pA1, tA0, tA1, tA2, 1); \
        int4v pA3 = __builtin_amdgcn_mfma_i32_16x16x64_i8((cA), bq[3], zc, 0, 0, 0); \
        T3R4(pB1, tB0, tB1, tB2, 1); \
        int4v pB3 = __builtin_amdgcn_mfma_i32_16x16x64_i8((cB), bq[3], zc, 0, 0, 0); \
        T3R4(pA2, tA0, tA1, tA2, 2); \
        T3R4(pB2, tB0, tB1, tB2, 2); \
        T3R4(pA3, tA0, tA1, tA2, 3); \
        T3R4(pB3, tB0, tB1, tB2, 3); } while (0)

    int4v caA = *(const int4v*)(&stile[0][0] + rd);
    int4v caB = *(const int4v*)(&stile[1][0] + rd);
    for (int k = 0; k < 10; ++k) {            // pairs (0,1)..(18,19)
        int4v naA = *(const int4v*)(&stile[2 * k + 2][0] + rd);
        int4v naB = *(const int4v*)(&stile[2 * k + 3][0] + rd);
        PROCPAIR(caA, caB);
        caA = naA; caB = naB;
    }
    {   // pair (20,21), prefetch 22 only (no out-of-range slot read)
        int4v naA = *(const int4v*)(&stile[22][0] + rd);
        PROCPAIR(caA, caB);
        caA = naA;
    }
    {   // tail tile 22 -> bank A
        int4v pA0 = __builtin_amdgcn_mfma_i32_16x16x64_i8(caA, bq[0], zc, 0, 0, 0);
        int4v pA1 = __builtin_amdgcn_mfma_i32_16x16x64_i8(caA, bq[1], zc, 0, 0, 0);
        int4v pA2 = __builtin_amdgcn_mfma_i32_16x16x64_i8(caA, bq[2], zc, 0, 0, 0);
        int4v pA3 = __builtin_amdgcn_mfma_i32_16x16x64_i8(caA, bq[3], zc, 0, 0, 0);
        T3R4(pA0, tA0, tA1, tA2, 0); T3R4(pA1, tA0, tA1, tA2, 1);
        T3R4(pA2, tA0, tA1, tA2, 2); T3R4(pA3, tA0, tA1, tA2, 3);
    }
#undef PROCPAIR

    const float INV = 1.0f / 16129.0f;
#pragma unroll
    for (int i = 0; i < 4; ++i) {
        int a0 = tA0[i], a1 = tA1[i], a2 = tA2[i];
        T3R(tB0[i], a0, a1, a2);
        T3R(tB1[i], a0, a1, a2);
        T3R(tB2[i], a0, a1, a2);
#pragma unroll
        for (int mk = 16; mk <= 32; mk <<= 1) {
            int c0 = __shfl_xor(a0, mk, 64);
            int c1 = __shfl_xor(a1, mk, 64);
            int c2 = __shfl_xor(a2, mk, 64);
            T3R(c0, a0, a1, a2);
            T3R(c1, a0, a1, a2);
            T3R(c2, a0, a1, a2);
        }
        if (hi4 == 0) {
            int x = (xg * 4 + i) * 16 + lo16;
            unsigned short* dst = gtop3 + ((size_t)(bid * QROWS + x) * NSLICE + ys) * 3;
            dst[0] = f2bf((float)a0 * INV);
            dst[1] = f2bf((float)a1 * INV);
            dst[2] = f2bf((float)a2 * INV);
        }
    }
}

// DIAGNOSTIC 2: r11 body with forced v_max_i32 (T3V). Writes scratch.
__global__ __launch_bounds__(448, 4) void dn4_vmax(const char* __restrict__ Qn,
                                                   const char* __restrict__ Sn,
                                                   unsigned short* __restrict__ gtop3) {
    __shared__ __align__(16) char stile[NT_S][TILE_B];
    SIM_PROLOGUE
    int t0[4], t1[4], t2[4];
#pragma unroll
    for (int i = 0; i < 4; ++i) { t0[i] = INT_MIN; t1[i] = INT_MIN; t2[i] = INT_MIN; }

    int4v ca = *(const int4v*)(&stile[0][0] + rd);
    for (int tt = 0; tt < NT_S; ++tt) {
        int4v na = ca;
        if (tt + 1 < NT_S) na = *(const int4v*)(&stile[tt + 1][0] + rd);
        int4v pA = __builtin_amdgcn_mfma_i32_16x16x64_i8(ca, bq[0], zc, 0, 0, 0);
        int4v pB = __builtin_amdgcn_mfma_i32_16x16x64_i8(ca, bq[1], zc, 0, 0, 0);
        T3V4(pA, t0, t1, t2, 0);
        int4v pC = __builtin_amdgcn_mfma_i32_16x16x64_i8(ca, bq[2], zc, 0, 0, 0);
        T3V4(pB, t0, t1, t2, 1);
        int4v pD = __builtin_amdgcn_mfma_i32_16x16x64_i8(ca, bq[3], zc, 0, 0, 0);
        T3V4(pC, t0, t1, t2, 2);
        T3V4(pD, t0, t1, t2, 3);
        ca = na;
    }

    const float INV = 1.0f / 16129.0f;
#pragma unroll
    for (int i = 0; i < 4; ++i) {
        int a0 = t0[i], a1 = t1[i], a2 = t2[i];
#pragma unroll
        for (int mk = 16; mk <= 32; mk <<= 1) {
            int c0 = __shfl_xor(a0, mk, 64);
            int c1 = __shfl_xor(a1, mk, 64);
            int c2 = __shfl_xor(a2, mk, 64);
            T3V(c0, a0, a1, a2);
            T3V(c1, a0, a1, a2);
            T3V(c2, a0, a1, a2);
        }
        if (hi4 == 0) {
            int x = (xg * 4 + i) * 16 + lo16;
            unsigned short* dst = gtop3 + ((size_t)(bid * QROWS + x) * NSLICE + ys) * 3;
            dst[0] = f2bf((float)a0 * INV);
            dst[1] = f2bf((float)a1 * INV);
            dst[2] = f2bf((float)a2 * INV);
        }
    }
}

// Kernel C: merge the 6 y-slices per (bid,x), sum top-3, block-reduce -> out[bid]
__global__ __launch_bounds__(448) void dn4_merge(const unsigned short* __restrict__ gtop3,
                                                 float* __restrict__ out) {
    __shared__ float red[7];
    int bid = blockIdx.x;
    int t = threadIdx.x, lane = t & 63, wv = t >> 6;
    const unsigned* p = (const unsigned*)(gtop3 + (size_t)(bid * QROWS + t) * (NSLICE * 3));
    float v[18];
#pragma unroll
    for (int j = 0; j < 9; ++j) {
        unsigned u = p[j];
        v[2 * j]     = bf2f((unsigned short)(u & 0xffffu));
        v[2 * j + 1] = bf2f((unsigned short)(u >> 16));
    }
    float a0 = v[0], a1 = v[1], a2 = v[2];
#pragma unroll
    for (int j = 3; j < 18; ++j) T3F(v[j], a0, a1, a2);
    float s = (t < NPOS) ? (a0 + a1 + a2) : 0.f;
#pragma unroll
    for (int off = 32; off >= 1; off >>= 1) s += __shfl_xor(s, off, 64);
    if (lane == 0) red[wv] = s;
    __syncthreads();
    if (t == 0) {
        float tot = 0.f;
#pragma unroll
        for (int i = 0; i < 7; ++i) tot += red[i];
        out[bid] = tot;
    }
}

extern "C" void kernel_launch(void* const* d_in, const int* in_sizes, int n_in,
                              void* d_out, int out_size, void* d_ws, size_t ws_size,
                              hipStream_t stream) {
    const float* fm     = (const float*)d_in[0];
    const int*   elabel = (const int*)d_in[1];
    float* out = (float*)d_out;

    char* Qn = (char*)d_ws;                                   // 1.43 MB
    char* Sn = Qn + (size_t)NQIMG * QROWS * FDIM;             // 1.41 MB
    unsigned short* gtop3  = (unsigned short*)(Sn + (size_t)10 * SROWS * FDIM);  // 4.03 MB (real)
    unsigned short* gtop3b = gtop3 + (size_t)NBLK * QROWS * NSLICE * 3;          // 4.03 MB (scratch)

    int nthreads = NIMG * NPOS;
    dn4_normalize<<<(nthreads + 255) / 256, 256, 0, stream>>>(fm, elabel, Qn, Sn, out);
    dn4_sim_mfma<<<NBLK_SIM, 448, 0, stream>>>(Qn, Sn, gtop3);   // REAL (r11-exact)
    dn4_pipe<<<NBLK_SIM, 448, 0, stream>>>(Qn, Sn, gtop3b);      // diag: dual-bank interleave
    dn4_vmax<<<NBLK_SIM, 448, 0, stream>>>(Qn, Sn, gtop3b);      // diag: forced v_max_i32
    dn4_merge<<<NBLK, 448, 0, stream>>>(gtop3, out);
}

// Round 16
// 48.337 us; speedup vs baseline: 2.8115x; 2.4521x over previous
//
#include <hip/hip_runtime.h>
#include <hip/hip_bf16.h>
#include <math.h>
#include <limits.h>

// Problem constants (fixed by setup_inputs)
#define BS 2
#define NW 5
#define NS 5
#define NQ 5
#define FDIM 64
#define FH 21
#define FW 21
#define NPOS (FH*FW)            // 441
#define NIMG (BS*NW*(NS+NQ))    // 100
#define NQIMG 50
#define IMG_ELEMS (FDIM*NPOS)   // 28224
#define NY (NS*NPOS)            // 2205
#define QROWS 448               // 441 padded to 28*16
#define SROWS 2208              // 138 tiles of 16 rows; rows 2205..2207 zeroed
#define NSLICE 6                // y split: 138 = 6 * 23
#define NT_S 23                 // y-tiles per slice
#define NBLK 250
#define NBLK_SIM (NBLK*NSLICE)  // 1500
#define TILE_B 1024             // 16 rows x 64 B (i8) per tile

typedef __attribute__((ext_vector_type(4))) int int4v;

static __device__ __forceinline__ unsigned short f2bf(float x) {
    union { float f; unsigned u; } v; v.f = x;
    unsigned r = v.u + 0x7fffu + ((v.u >> 16) & 1u);
    return (unsigned short)(r >> 16);
}

static __device__ __forceinline__ float bf2f(unsigned short u) {
    union { unsigned u; float f; } v; v.u = ((unsigned)u) << 16;
    return v.f;
}

static __device__ __forceinline__ void gload_lds16(const void* g, void* l) {
    __builtin_amdgcn_global_load_lds((const __attribute__((address_space(1))) void*)g,
                                     (__attribute__((address_space(3))) void*)l, 16, 0, 0);
}

static __device__ __forceinline__ int med3i(int a, int b, int c) {
    int r;
    asm("v_med3_i32 %0, %1, %2, %3" : "=v"(r) : "v"(a), "v"(b), "v"(c));
    return r;
}

// r11-proven top-3 insert (ternary max): a0>=a1>=a2 sorted invariant
#define T3R(d, a0, a1, a2) do { \
    int _n0 = ((d) > (a0)) ? (d) : (a0); \
    int _n1 = med3i((d), (a0), (a1)); \
    int _n2 = med3i((d), (a1), (a2)); \
    (a0) = _n0; (a1) = _n1; (a2) = _n2; } while (0)

#define T3R4(p, s0, s1, s2, i) do { \
    T3R((p)[0], s0[i], s1[i], s2[i]); \
    T3R((p)[1], s0[i], s1[i], s2[i]); \
    T3R((p)[2], s0[i], s1[i], s2[i]); \
    T3R((p)[3], s0[i], s1[i], s2[i]); } while (0)

// float top-3 insert for the merge kernel
#define T3F(d, a0, a1, a2) do { \
    float _n0 = fmaxf((d), (a0)); \
    float _n1 = __builtin_amdgcn_fmed3f((d), (a0), (a1)); \
    float _n2 = __builtin_amdgcn_fmed3f((d), (a1), (a2)); \
    (a0) = _n0; (a1) = _n1; (a2) = _n2; } while (0)

// Kernel A: L2-normalize per (img,pos), quantize to i8 (scale 127, RNE).
__global__ __launch_bounds__(256) void dn4_normalize(const float* __restrict__ fm,
                                                     const int* __restrict__ elabel,
                                                     char* __restrict__ Qn,
                                                     char* __restrict__ Sn,
                                                     float* __restrict__ out) {
    int gid = blockIdx.x * blockDim.x + threadIdx.x;
    if (gid < 50) {   // label pass-through: out[250+gid]
        int bb = gid / 25, rem = gid % 25, wq = rem / 5, qi = rem % 5;
        out[250 + gid] = (float)elabel[(bb * NW + wq) * (NS + NQ) + NS + qi];
    }
    if (gid < 120) {  // zero S pad rows 2205..2207: 10 mats x 3 rows x 4 int4
        int mat = gid / 12, rr = (gid % 12) >> 2, k = gid & 3;
        int4v zv = {0, 0, 0, 0};
        *(int4v*)(Sn + (size_t)mat * (SROWS * FDIM) + (size_t)(NY + rr) * FDIM + k * 16) = zv;
    }
    if (gid >= NIMG * NPOS) return;
    int img = gid / NPOS;
    int pos = gid - img * NPOS;
    const float* src = fm + (size_t)img * IMG_ELEMS + pos;
    float v[FDIM];
    float ss = 0.f;
#pragma unroll
    for (int c = 0; c < FDIM; ++c) {
        float x = src[(size_t)c * NPOS];
        v[c] = x;
        ss += x * x;
    }
    float rn = 127.0f / (sqrtf(ss) + 1e-12f);
    int w[16];
#pragma unroll
    for (int k = 0; k < 16; ++k) {
        int q0 = __float2int_rn(v[4 * k]     * rn);
        int q1 = __float2int_rn(v[4 * k + 1] * rn);
        int q2 = __float2int_rn(v[4 * k + 2] * rn);
        int q3 = __float2int_rn(v[4 * k + 3] * rn);
        w[k] = (q0 & 0xff) | ((q1 & 0xff) << 8) | ((q2 & 0xff) << 16) | (q3 << 24);
    }
    char* dst;
    int i10 = img % 10;
    if (i10 < NS) {
        int bw = img / 10;
        dst = Sn + (size_t)bw * (SROWS * FDIM) + (size_t)(i10 * NPOS + pos) * FDIM;
    } else {
        int qidx = (img / 10) * NQ + (i10 - NS);
        dst = Qn + (size_t)qidx * (QROWS * FDIM) + (size_t)pos * FDIM;
    }
#pragma unroll
    for (int k = 0; k < 4; ++k) {
        int4v t = {w[4 * k], w[4 * k + 1], w[4 * k + 2], w[4 * k + 3]};
        *(int4v*)(dst + 16 * k) = t;
    }
}

// Kernel B (REAL — promoted r15 dn4_pipe, measured ~26-28 µs): 1500 blocks =
// (bid, y-slice); 448 threads = 7 waves (wave = xg, 4 x-tiles each). 23-tile
// S-slice staged once into LDS (swizzled), then a barrier-free DUAL-BANK pair
// loop: y-tiles processed two at a time with separate top-3 state banks, so
// 8 independent MFMAs are in flight and bank-A's T3R chain covers bank-B's
// MFMA latency (and vice versa). Banks merged at the end (selection is
// order-independent -> bit-identical to r11's output).
__global__ __launch_bounds__(448, 4) void dn4_sim_mfma(const char* __restrict__ Qn,
                                                       const char* __restrict__ Sn,
                                                       unsigned short* __restrict__ gtop3) {
    __shared__ __align__(16) char stile[NT_S][TILE_B];   // 23,552 B

    // m204 bijective chunked XCD swizzle over 1500 units (1500 = 8*187+4)
    int orig = blockIdx.x;
    int xcd = orig & 7, idx = orig >> 3;
    int unit = (xcd < 4 ? xcd * 188 : 4 * 188 + (xcd - 4) * 187) + idx;
    int bid = unit / NSLICE, ys = unit % NSLICE;

    int w = bid % NW;
    int q = (bid / NW) % (NW * NQ);
    int b = bid / (NW * NW * NQ);
    int wq = q / NQ, qi = q % NQ;
    int qidx = (b * NW + wq) * NQ + qi;

    const char* qbase = Qn + (size_t)qidx * (QROWS * FDIM);
    const char* sbase = Sn + (size_t)(b * NW + w) * (SROWS * FDIM);

    int t = threadIdx.x;
    int lane = t & 63, xg = t >> 6;
    int lo16 = lane & 15, hi4 = lane >> 4;

    // Stage source pre-swizzle: LDS linear [row][c] gets global [row][c ^ ((row>>1)&3)]
    int stg0 = ((lane >> 2) * FDIM) + ((((lane & 3) ^ ((lane >> 3) & 3)) << 4));
    int tbase = ys * NT_S;

    for (int i = xg; i < NT_S; i += 7)
        gload_lds16(sbase + (size_t)(tbase + i) * TILE_B + stg0, &stile[i][0]);

    // B fragments (Q): col = lo16 -> x = xt*16+lo16, k = hi4*16 .. +16
    int4v bq[4];
#pragma unroll
    for (int i = 0; i < 4; ++i) {
        int xt = xg * 4 + i;
        bq[i] = *(const int4v*)(qbase + (size_t)(xt * 16 + lo16) * FDIM + hi4 * 16);
    }

    asm volatile("s_waitcnt vmcnt(0)" ::: "memory");
    __syncthreads();   // the ONLY barrier

    int tA0[4], tA1[4], tA2[4], tB0[4], tB1[4], tB2[4];
#pragma unroll
    for (int i = 0; i < 4; ++i) {
        tA0[i] = INT_MIN; tA1[i] = INT_MIN; tA2[i] = INT_MIN;
        tB0[i] = INT_MIN; tB1[i] = INT_MIN; tB2[i] = INT_MIN;
    }

    int4v zc = {0, 0, 0, 0};

    // Swizzled read: row lo16, want col hi4 -> read hi4 ^ ((lo16>>1)&3)
    int rd = lo16 * FDIM + ((hi4 ^ ((lo16 >> 1) & 3)) << 4);

#define PROCPAIR(cA, cB) do { \
        int4v pA0 = __builtin_amdgcn_mfma_i32_16x16x64_i8((cA), bq[0], zc, 0, 0, 0); \
        int4v pB0 = __builtin_amdgcn_mfma_i32_16x16x64_i8((cB), bq[0], zc, 0, 0, 0); \
        int4v pA1 = __builtin_amdgcn_mfma_i32_16x16x64_i8((cA), bq[1], zc, 0, 0, 0); \
        int4v pB1 = __builtin_amdgcn_mfma_i32_16x16x64_i8((cB), bq[1], zc, 0, 0, 0); \
        T3R4(pA0, tA0, tA1, tA2, 0); \
        int4v pA2 = __builtin_amdgcn_mfma_i32_16x16x64_i8((cA), bq[2], zc, 0, 0, 0); \
        T3R4(pB0, tB0, tB1, tB2, 0); \
        int4v pB2 = __builtin_amdgcn_mfma_i32_16x16x64_i8((cB), bq[2], zc, 0, 0, 0); \
        T3R4(pA1, tA0, tA1, tA2, 1); \
        int4v pA3 = __builtin_amdgcn_mfma_i32_16x16x64_i8((cA), bq[3], zc, 0, 0, 0); \
        T3R4(pB1, tB0, tB1, tB2, 1); \
        int4v pB3 = __builtin_amdgcn_mfma_i32_16x16x64_i8((cB), bq[3], zc, 0, 0, 0); \
        T3R4(pA2, tA0, tA1, tA2, 2); \
        T3R4(pB2, tB0, tB1, tB2, 2); \
        T3R4(pA3, tA0, tA1, tA2, 3); \
        T3R4(pB3, tB0, tB1, tB2, 3); } while (0)

    int4v caA = *(const int4v*)(&stile[0][0] + rd);
    int4v caB = *(const int4v*)(&stile[1][0] + rd);
    for (int k = 0; k < 10; ++k) {            // pairs (0,1)..(18,19)
        int4v naA = *(const int4v*)(&stile[2 * k + 2][0] + rd);
        int4v naB = *(const int4v*)(&stile[2 * k + 3][0] + rd);
        PROCPAIR(caA, caB);
        caA = naA; caB = naB;
    }
    {   // pair (20,21), prefetch 22 only (no out-of-range slot read)
        int4v naA = *(const int4v*)(&stile[22][0] + rd);
        PROCPAIR(caA, caB);
        caA = naA;
    }
    {   // tail tile 22 -> bank A
        int4v pA0 = __builtin_amdgcn_mfma_i32_16x16x64_i8(caA, bq[0], zc, 0, 0, 0);
        int4v pA1 = __builtin_amdgcn_mfma_i32_16x16x64_i8(caA, bq[1], zc, 0, 0, 0);
        int4v pA2 = __builtin_amdgcn_mfma_i32_16x16x64_i8(caA, bq[2], zc, 0, 0, 0);
        int4v pA3 = __builtin_amdgcn_mfma_i32_16x16x64_i8(caA, bq[3], zc, 0, 0, 0);
        T3R4(pA0, tA0, tA1, tA2, 0); T3R4(pA1, tA0, tA1, tA2, 1);
        T3R4(pA2, tA0, tA1, tA2, 2); T3R4(pA3, tA0, tA1, tA2, 3);
    }
#undef PROCPAIR

    // Merge bank B into A, then across the 4 y-quarter lane-groups; write bf16
    const float INV = 1.0f / 16129.0f;   // 1/127^2
#pragma unroll
    for (int i = 0; i < 4; ++i) {
        int a0 = tA0[i], a1 = tA1[i], a2 = tA2[i];
        T3R(tB0[i], a0, a1, a2);
        T3R(tB1[i], a0, a1, a2);
        T3R(tB2[i], a0, a1, a2);
#pragma unroll
        for (int mk = 16; mk <= 32; mk <<= 1) {
            int c0 = __shfl_xor(a0, mk, 64);
            int c1 = __shfl_xor(a1, mk, 64);
            int c2 = __shfl_xor(a2, mk, 64);
            T3R(c0, a0, a1, a2);
            T3R(c1, a0, a1, a2);
            T3R(c2, a0, a1, a2);
        }
        if (hi4 == 0) {
            int x = (xg * 4 + i) * 16 + lo16;
            unsigned short* dst = gtop3 + ((size_t)(bid * QROWS + x) * NSLICE + ys) * 3;
            dst[0] = f2bf((float)a0 * INV);
            dst[1] = f2bf((float)a1 * INV);
            dst[2] = f2bf((float)a2 * INV);
        }
    }
}

// Kernel C: merge the 6 y-slices per (bid,x), sum top-3, block-reduce -> out[bid]
__global__ __launch_bounds__(448) void dn4_merge(const unsigned short* __restrict__ gtop3,
                                                 float* __restrict__ out) {
    __shared__ float red[7];
    int bid = blockIdx.x;
    int t = threadIdx.x, lane = t & 63, wv = t >> 6;
    const unsigned* p = (const unsigned*)(gtop3 + (size_t)(bid * QROWS + t) * (NSLICE * 3));
    float v[18];
#pragma unroll
    for (int j = 0; j < 9; ++j) {
        unsigned u = p[j];
        v[2 * j]     = bf2f((unsigned short)(u & 0xffffu));
        v[2 * j + 1] = bf2f((unsigned short)(u >> 16));
    }
    float a0 = v[0], a1 = v[1], a2 = v[2];
#pragma unroll
    for (int j = 3; j < 18; ++j) T3F(v[j], a0, a1, a2);
    float s = (t < NPOS) ? (a0 + a1 + a2) : 0.f;
#pragma unroll
    for (int off = 32; off >= 1; off >>= 1) s += __shfl_xor(s, off, 64);
    if (lane == 0) red[wv] = s;
    __syncthreads();
    if (t == 0) {
        float tot = 0.f;
#pragma unroll
        for (int i = 0; i < 7; ++i) tot += red[i];
        out[bid] = tot;
    }
}

extern "C" void kernel_launch(void* const* d_in, const int* in_sizes, int n_in,
                              void* d_out, int out_size, void* d_ws, size_t ws_size,
                              hipStream_t stream) {
    const float* fm     = (const float*)d_in[0];
    const int*   elabel = (const int*)d_in[1];
    float* out = (float*)d_out;

    char* Qn = (char*)d_ws;                                   // 1.43 MB
    char* Sn = Qn + (size_t)NQIMG * QROWS * FDIM;             // 1.41 MB
    unsigned short* gtop3 = (unsigned short*)(Sn + (size_t)10 * SROWS * FDIM);  // 4.03 MB

    int nthreads = NIMG * NPOS;
    dn4_normalize<<<(nthreads + 255) / 256, 256, 0, stream>>>(fm, elabel, Qn, Sn, out);
    dn4_sim_mfma<<<NBLK_SIM, 448, 0, stream>>>(Qn, Sn, gtop3);
    dn4_merge<<<NBLK, 448, 0, stream>>>(gtop3, out);
}

// Round 17
// 47.981 us; speedup vs baseline: 2.8323x; 1.0074x over previous
//
#include <hip/hip_runtime.h>
#include <hip/hip_bf16.h>
#include <math.h>
#include <limits.h>

// Problem constants (fixed by setup_inputs)
#define BS 2
#define NW 5
#define NS 5
#define NQ 5
#define FDIM 64
#define FH 21
#define FW 21
#define NPOS (FH*FW)            // 441
#define NIMG (BS*NW*(NS+NQ))    // 100
#define NQIMG 50
#define IMG_ELEMS (FDIM*NPOS)   // 28224
#define NY (NS*NPOS)            // 2205
#define QROWS 448               // 441 padded to 28*16
#define SROWS 2208              // 138 tiles of 16 rows; rows 2205..2207 zeroed
#define NSLICE 6                // y split: 138 = 6 * 23
#define NT_S 23                 // y-tiles per slice
#define NBLK 250
#define NBLK_SIM (NBLK*NSLICE)  // 1500
#define TILE_B 1024             // 16 rows x 64 B (i8) per tile

typedef __attribute__((ext_vector_type(4))) int int4v;

static __device__ __forceinline__ unsigned short f2bf(float x) {
    union { float f; unsigned u; } v; v.f = x;
    unsigned r = v.u + 0x7fffu + ((v.u >> 16) & 1u);
    return (unsigned short)(r >> 16);
}

static __device__ __forceinline__ float bf2f(unsigned short u) {
    union { unsigned u; float f; } v; v.u = ((unsigned)u) << 16;
    return v.f;
}

static __device__ __forceinline__ void gload_lds16(const void* g, void* l) {
    __builtin_amdgcn_global_load_lds((const __attribute__((address_space(1))) void*)g,
                                     (__attribute__((address_space(3))) void*)l, 16, 0, 0);
}

static __device__ __forceinline__ int med3i(int a, int b, int c) {
    int r;
    asm("v_med3_i32 %0, %1, %2, %3" : "=v"(r) : "v"(a), "v"(b), "v"(c));
    return r;
}

// r11-proven top-3 insert (ternary max): a0>=a1>=a2 sorted invariant
#define T3R(d, a0, a1, a2) do { \
    int _n0 = ((d) > (a0)) ? (d) : (a0); \
    int _n1 = med3i((d), (a0), (a1)); \
    int _n2 = med3i((d), (a1), (a2)); \
    (a0) = _n0; (a1) = _n1; (a2) = _n2; } while (0)

#define T3R4(p, s0, s1, s2, i) do { \
    T3R((p)[0], s0[i], s1[i], s2[i]); \
    T3R((p)[1], s0[i], s1[i], s2[i]); \
    T3R((p)[2], s0[i], s1[i], s2[i]); \
    T3R((p)[3], s0[i], s1[i], s2[i]); } while (0)

// float top-3 insert for the merge kernel
#define T3F(d, a0, a1, a2) do { \
    float _n0 = fmaxf((d), (a0)); \
    float _n1 = __builtin_amdgcn_fmed3f((d), (a0), (a1)); \
    float _n2 = __builtin_amdgcn_fmed3f((d), (a1), (a2)); \
    (a0) = _n0; (a1) = _n1; (a2) = _n2; } while (0)

// Kernel A: L2-normalize per (img,pos), quantize to i8 (scale 127, RNE).
__global__ __launch_bounds__(256) void dn4_normalize(const float* __restrict__ fm,
                                                     const int* __restrict__ elabel,
                                                     char* __restrict__ Qn,
                                                     char* __restrict__ Sn,
                                                     float* __restrict__ out) {
    int gid = blockIdx.x * blockDim.x + threadIdx.x;
    if (gid < 50) {   // label pass-through: out[250+gid]
        int bb = gid / 25, rem = gid % 25, wq = rem / 5, qi = rem % 5;
        out[250 + gid] = (float)elabel[(bb * NW + wq) * (NS + NQ) + NS + qi];
    }
    if (gid < 120) {  // zero S pad rows 2205..2207: 10 mats x 3 rows x 4 int4
        int mat = gid / 12, rr = (gid % 12) >> 2, k = gid & 3;
        int4v zv = {0, 0, 0, 0};
        *(int4v*)(Sn + (size_t)mat * (SROWS * FDIM) + (size_t)(NY + rr) * FDIM + k * 16) = zv;
    }
    if (gid >= NIMG * NPOS) return;
    int img = gid / NPOS;
    int pos = gid - img * NPOS;
    const float* src = fm + (size_t)img * IMG_ELEMS + pos;
    float v[FDIM];
    float ss = 0.f;
#pragma unroll
    for (int c = 0; c < FDIM; ++c) {
        float x = src[(size_t)c * NPOS];
        v[c] = x;
        ss += x * x;
    }
    float rn = 127.0f / (sqrtf(ss) + 1e-12f);
    int w[16];
#pragma unroll
    for (int k = 0; k < 16; ++k) {
        int q0 = __float2int_rn(v[4 * k]     * rn);
        int q1 = __float2int_rn(v[4 * k + 1] * rn);
        int q2 = __float2int_rn(v[4 * k + 2] * rn);
        int q3 = __float2int_rn(v[4 * k + 3] * rn);
        w[k] = (q0 & 0xff) | ((q1 & 0xff) << 8) | ((q2 & 0xff) << 16) | (q3 << 24);
    }
    char* dst;
    int i10 = img % 10;
    if (i10 < NS) {
        int bw = img / 10;
        dst = Sn + (size_t)bw * (SROWS * FDIM) + (size_t)(i10 * NPOS + pos) * FDIM;
    } else {
        int qidx = (img / 10) * NQ + (i10 - NS);
        dst = Qn + (size_t)qidx * (QROWS * FDIM) + (size_t)pos * FDIM;
    }
#pragma unroll
    for (int k = 0; k < 4; ++k) {
        int4v t = {w[4 * k], w[4 * k + 1], w[4 * k + 2], w[4 * k + 3]};
        *(int4v*)(dst + 16 * k) = t;
    }
}

// Kernel B: 1500 blocks = (bid, y-slice); 448 threads = 7 waves (wave = xg,
// 4 x-tiles each). 23-tile S-slice staged once into LDS (swizzled). Inner loop
// is a CROSS-ITERATION software pipeline: f0..f7 hold the 8 MFMA results of
// y-tile pair k ACROSS the loop back-edge; iteration k+1 consumes f_i (T3R)
// then immediately reissues it for pair k+1. The loop-carried liveness forces
// the register allocator to keep 8 MFMAs in flight (r16's failure mode was
// regalloc collapsing the in-iteration dual-bank ILP back to serial).
__global__ __launch_bounds__(448, 4) void dn4_sim_mfma(const char* __restrict__ Qn,
                                                       const char* __restrict__ Sn,
                                                       unsigned short* __restrict__ gtop3) {
    __shared__ __align__(16) char stile[NT_S][TILE_B];   // 23,552 B

    // m204 bijective chunked XCD swizzle over 1500 units (1500 = 8*187+4)
    int orig = blockIdx.x;
    int xcd = orig & 7, idx = orig >> 3;
    int unit = (xcd < 4 ? xcd * 188 : 4 * 188 + (xcd - 4) * 187) + idx;
    int bid = unit / NSLICE, ys = unit % NSLICE;

    int w = bid % NW;
    int q = (bid / NW) % (NW * NQ);
    int b = bid / (NW * NW * NQ);
    int wq = q / NQ, qi = q % NQ;
    int qidx = (b * NW + wq) * NQ + qi;

    const char* qbase = Qn + (size_t)qidx * (QROWS * FDIM);
    const char* sbase = Sn + (size_t)(b * NW + w) * (SROWS * FDIM);

    int t = threadIdx.x;
    int lane = t & 63, xg = t >> 6;
    int lo16 = lane & 15, hi4 = lane >> 4;

    // Stage source pre-swizzle: LDS linear [row][c] gets global [row][c ^ ((row>>1)&3)]
    int stg0 = ((lane >> 2) * FDIM) + ((((lane & 3) ^ ((lane >> 3) & 3)) << 4));
    int tbase = ys * NT_S;

    for (int i = xg; i < NT_S; i += 7)
        gload_lds16(sbase + (size_t)(tbase + i) * TILE_B + stg0, &stile[i][0]);

    // B fragments (Q): col = lo16 -> x = xt*16+lo16, k = hi4*16 .. +16
    int4v bq[4];
#pragma unroll
    for (int i = 0; i < 4; ++i) {
        int xt = xg * 4 + i;
        bq[i] = *(const int4v*)(qbase + (size_t)(xt * 16 + lo16) * FDIM + hi4 * 16);
    }

    asm volatile("s_waitcnt vmcnt(0)" ::: "memory");
    __syncthreads();   // the ONLY barrier

    int tA0[4], tA1[4], tA2[4], tB0[4], tB1[4], tB2[4];
#pragma unroll
    for (int i = 0; i < 4; ++i) {
        tA0[i] = INT_MIN; tA1[i] = INT_MIN; tA2[i] = INT_MIN;
        tB0[i] = INT_MIN; tB1[i] = INT_MIN; tB2[i] = INT_MIN;
    }

    int4v zc = {0, 0, 0, 0};

    // Swizzled read: row lo16, want col hi4 -> read hi4 ^ ((lo16>>1)&3)
    int rd = lo16 * FDIM + ((hi4 ^ ((lo16 >> 1) & 3)) << 4);

    // ---- software pipeline: issue pair 0, then consume(k-1)+issue(k) ----
    int4v caA = *(const int4v*)(&stile[0][0] + rd);
    int4v caB = *(const int4v*)(&stile[1][0] + rd);
    int4v f0 = __builtin_amdgcn_mfma_i32_16x16x64_i8(caA, bq[0], zc, 0, 0, 0);
    int4v f1 = __builtin_amdgcn_mfma_i32_16x16x64_i8(caB, bq[0], zc, 0, 0, 0);
    int4v f2 = __builtin_amdgcn_mfma_i32_16x16x64_i8(caA, bq[1], zc, 0, 0, 0);
    int4v f3 = __builtin_amdgcn_mfma_i32_16x16x64_i8(caB, bq[1], zc, 0, 0, 0);
    int4v f4 = __builtin_amdgcn_mfma_i32_16x16x64_i8(caA, bq[2], zc, 0, 0, 0);
    int4v f5 = __builtin_amdgcn_mfma_i32_16x16x64_i8(caB, bq[2], zc, 0, 0, 0);
    int4v f6 = __builtin_amdgcn_mfma_i32_16x16x64_i8(caA, bq[3], zc, 0, 0, 0);
    int4v f7 = __builtin_amdgcn_mfma_i32_16x16x64_i8(caB, bq[3], zc, 0, 0, 0);
    caA = *(const int4v*)(&stile[2][0] + rd);
    caB = *(const int4v*)(&stile[3][0] + rd);

    // iterations k=1..9: consume pair k-1 from f, reissue f for pair k (tiles 2k,2k+1)
    for (int k = 1; k < 10; ++k) {
        int4v naA = *(const int4v*)(&stile[2 * k + 2][0] + rd);
        int4v naB = *(const int4v*)(&stile[2 * k + 3][0] + rd);
        T3R4(f0, tA0, tA1, tA2, 0); f0 = __builtin_amdgcn_mfma_i32_16x16x64_i8(caA, bq[0], zc, 0, 0, 0);
        T3R4(f1, tB0, tB1, tB2, 0); f1 = __builtin_amdgcn_mfma_i32_16x16x64_i8(caB, bq[0], zc, 0, 0, 0);
        T3R4(f2, tA0, tA1, tA2, 1); f2 = __builtin_amdgcn_mfma_i32_16x16x64_i8(caA, bq[1], zc, 0, 0, 0);
        T3R4(f3, tB0, tB1, tB2, 1); f3 = __builtin_amdgcn_mfma_i32_16x16x64_i8(caB, bq[1], zc, 0, 0, 0);
        T3R4(f4, tA0, tA1, tA2, 2); f4 = __builtin_amdgcn_mfma_i32_16x16x64_i8(caA, bq[2], zc, 0, 0, 0);
        T3R4(f5, tB0, tB1, tB2, 2); f5 = __builtin_amdgcn_mfma_i32_16x16x64_i8(caB, bq[2], zc, 0, 0, 0);
        T3R4(f6, tA0, tA1, tA2, 3); f6 = __builtin_amdgcn_mfma_i32_16x16x64_i8(caA, bq[3], zc, 0, 0, 0);
        T3R4(f7, tB0, tB1, tB2, 3); f7 = __builtin_amdgcn_mfma_i32_16x16x64_i8(caB, bq[3], zc, 0, 0, 0);
        caA = naA; caB = naB;
    }
    {   // k=10: consume pair 9, reissue for pair 10 (tiles 20,21); prefetch tile 22
        int4v naA = *(const int4v*)(&stile[22][0] + rd);
        T3R4(f0, tA0, tA1, tA2, 0); f0 = __builtin_amdgcn_mfma_i32_16x16x64_i8(caA, bq[0], zc, 0, 0, 0);
        T3R4(f1, tB0, tB1, tB2, 0); f1 = __builtin_amdgcn_mfma_i32_16x16x64_i8(caB, bq[0], zc, 0, 0, 0);
        T3R4(f2, tA0, tA1, tA2, 1); f2 = __builtin_amdgcn_mfma_i32_16x16x64_i8(caA, bq[1], zc, 0, 0, 0);
        T3R4(f3, tB0, tB1, tB2, 1); f3 = __builtin_amdgcn_mfma_i32_16x16x64_i8(caB, bq[1], zc, 0, 0, 0);
        T3R4(f4, tA0, tA1, tA2, 2); f4 = __builtin_amdgcn_mfma_i32_16x16x64_i8(caA, bq[2], zc, 0, 0, 0);
        T3R4(f5, tB0, tB1, tB2, 2); f5 = __builtin_amdgcn_mfma_i32_16x16x64_i8(caB, bq[2], zc, 0, 0, 0);
        T3R4(f6, tA0, tA1, tA2, 3); f6 = __builtin_amdgcn_mfma_i32_16x16x64_i8(caA, bq[3], zc, 0, 0, 0);
        T3R4(f7, tB0, tB1, tB2, 3); f7 = __builtin_amdgcn_mfma_i32_16x16x64_i8(caB, bq[3], zc, 0, 0, 0);
        caA = naA;
    }
    {   // consume pair 10; tail tile 22 (in caA): issue 4 + consume
        T3R4(f0, tA0, tA1, tA2, 0);
        int4v g0 = __builtin_amdgcn_mfma_i32_16x16x64_i8(caA, bq[0], zc, 0, 0, 0);
        T3R4(f1, tB0, tB1, tB2, 0);
        int4v g1 = __builtin_amdgcn_mfma_i32_16x16x64_i8(caA, bq[1], zc, 0, 0, 0);
        T3R4(f2, tA0, tA1, tA2, 1);
        int4v g2 = __builtin_amdgcn_mfma_i32_16x16x64_i8(caA, bq[2], zc, 0, 0, 0);
        T3R4(f3, tB0, tB1, tB2, 1);
        int4v g3 = __builtin_amdgcn_mfma_i32_16x16x64_i8(caA, bq[3], zc, 0, 0, 0);
        T3R4(f4, tA0, tA1, tA2, 2);
        T3R4(f5, tB0, tB1, tB2, 2);
        T3R4(f6, tA0, tA1, tA2, 3);
        T3R4(f7, tB0, tB1, tB2, 3);
        T3R4(g0, tA0, tA1, tA2, 0);
        T3R4(g1, tA0, tA1, tA2, 1);
        T3R4(g2, tA0, tA1, tA2, 2);
        T3R4(g3, tA0, tA1, tA2, 3);
    }

    // Merge bank B into A, then across the 4 y-quarter lane-groups; write bf16
    const float INV = 1.0f / 16129.0f;   // 1/127^2
#pragma unroll
    for (int i = 0; i < 4; ++i) {
        int a0 = tA0[i], a1 = tA1[i], a2 = tA2[i];
        T3R(tB0[i], a0, a1, a2);
        T3R(tB1[i], a0, a1, a2);
        T3R(tB2[i], a0, a1, a2);
#pragma unroll
        for (int mk = 16; mk <= 32; mk <<= 1) {
            int c0 = __shfl_xor(a0, mk, 64);
            int c1 = __shfl_xor(a1, mk, 64);
            int c2 = __shfl_xor(a2, mk, 64);
            T3R(c0, a0, a1, a2);
            T3R(c1, a0, a1, a2);
            T3R(c2, a0, a1, a2);
        }
        if (hi4 == 0) {
            int x = (xg * 4 + i) * 16 + lo16;
            unsigned short* dst = gtop3 + ((size_t)(bid * QROWS + x) * NSLICE + ys) * 3;
            dst[0] = f2bf((float)a0 * INV);
            dst[1] = f2bf((float)a1 * INV);
            dst[2] = f2bf((float)a2 * INV);
        }
    }
}

// Kernel C: merge the 6 y-slices per (bid,x), sum top-3, block-reduce -> out[bid]
__global__ __launch_bounds__(448) void dn4_merge(const unsigned short* __restrict__ gtop3,
                                                 float* __restrict__ out) {
    __shared__ float red[7];
    int bid = blockIdx.x;
    int t = threadIdx.x, lane = t & 63, wv = t >> 6;
    const unsigned* p = (const unsigned*)(gtop3 + (size_t)(bid * QROWS + t) * (NSLICE * 3));
    float v[18];
#pragma unroll
    for (int j = 0; j < 9; ++j) {
        unsigned u = p[j];
        v[2 * j]     = bf2f((unsigned short)(u & 0xffffu));
        v[2 * j + 1] = bf2f((unsigned short)(u >> 16));
    }
    float a0 = v[0], a1 = v[1], a2 = v[2];
#pragma unroll
    for (int j = 3; j < 18; ++j) T3F(v[j], a0, a1, a2);
    float s = (t < NPOS) ? (a0 + a1 + a2) : 0.f;
#pragma unroll
    for (int off = 32; off >= 1; off >>= 1) s += __shfl_xor(s, off, 64);
    if (lane == 0) red[wv] = s;
    __syncthreads();
    if (t == 0) {
        float tot = 0.f;
#pragma unroll
        for (int i = 0; i < 7; ++i) tot += red[i];
        out[bid] = tot;
    }
}

extern "C" void kernel_launch(void* const* d_in, const int* in_sizes, int n_in,
                              void* d_out, int out_size, void* d_ws, size_t ws_size,
                              hipStream_t stream) {
    const float* fm     = (const float*)d_in[0];
    const int*   elabel = (const int*)d_in[1];
    float* out = (float*)d_out;

    char* Qn = (char*)d_ws;                                   // 1.43 MB
    char* Sn = Qn + (size_t)NQIMG * QROWS * FDIM;             // 1.41 MB
    unsigned short* gtop3 = (unsigned short*)(Sn + (size_t)10 * SROWS * FDIM);  // 4.03 MB

    int nthreads = NIMG * NPOS;
    dn4_normalize<<<(nthreads + 255) / 256, 256, 0, stream>>>(fm, elabel, Qn, Sn, out);
    dn4_sim_mfma<<<NBLK_SIM, 448, 0, stream>>>(Qn, Sn, gtop3);
    dn4_merge<<<NBLK, 448, 0, stream>>>(gtop3, out);
}